// Round 9
// baseline (215.979 us; speedup 1.0000x reference)
//
#include <hip/hip_runtime.h>

typedef unsigned short u16;
typedef __attribute__((ext_vector_type(8))) __bf16 bf16x8;
typedef __attribute__((ext_vector_type(4))) float f32x4;
typedef __attribute__((ext_vector_type(4))) int   i32x4;

#define NLQ 32768          // N*Lq
#define WPN (384*256)      // proj weight elements
#define WON (256*256)      // out weight elements
#define FMU 3403264        // fm 32B-units = 13294*8*256/8

static __device__ __forceinline__ u16 f2bf(float f) {
    unsigned u = __float_as_uint(f);
    return (u16)((u + 0x7fffu + ((u >> 16) & 1u)) >> 16);   // RNE
}
static __device__ __forceinline__ uint pk2(float lo, float hi) {
    return (uint)f2bf(lo) | ((uint)f2bf(hi) << 16);
}

// ---------------------------------------------------------------------------
// Prep (one kernel, 3 grid sections):
//  A [0,1662):    fm f32 -> bf16. Per-thread 8 CONTIGUOUS 32B->16B units
//                 (256B read / 128B write), 16 loads in regs before stores.
//  B [1662,2174): query -> qbf[(n*4096+lq)*256+c] bf16 (transposed rows).
//  C [2174,2814): W transposes -> wtp[j][k], wto[j][k].
// ---------------------------------------------------------------------------
__global__ __launch_bounds__(256) void prep_kernel(
    const f32x4* __restrict__ fm, uint4* __restrict__ fmb,
    const float* __restrict__ query, uint4* __restrict__ qbf4,
    const float* __restrict__ W_off, const float* __restrict__ W_attn,
    const float* __restrict__ W_out,
    u16* __restrict__ wtp, u16* __restrict__ wto)
{
    const int b = blockIdx.x, t = threadIdx.x;
    if (b < 1662) {
        // exact tail: block 1661 has 1536 units = 192 threads * 8
        if (b == 1661 && t >= 192) return;
        const int base = b * 2048 + t * 8;
        f32x4 lo[8], hi[8];
#pragma unroll
        for (int j = 0; j < 8; ++j) {
            lo[j] = __builtin_nontemporal_load(fm + 2 * (base + j));
            hi[j] = __builtin_nontemporal_load(fm + 2 * (base + j) + 1);
        }
#pragma unroll
        for (int j = 0; j < 8; ++j) {
            uint4 r;
            r.x = pk2(lo[j].x, lo[j].y); r.y = pk2(lo[j].z, lo[j].w);
            r.z = pk2(hi[j].x, hi[j].y); r.w = pk2(hi[j].z, hi[j].w);
            fmb[base + j] = r;
        }
    } else if (b < 2174) {
        // 512 blocks * 2048 units = 1,048,576 units = 8,388,608 bf16 (exact)
        const int base = (b - 1662) * 2048 + t * 8;
        f32x4 lo[8], hi[8];
#pragma unroll
        for (int j = 0; j < 8; ++j) {
            int u = base + j;
            int gq = u >> 5;                 // dest row, (n*4096+lq) order
            int c  = (u & 31) * 8;
            int lq = gq & 4095, n = gq >> 12;
            const f32x4* src = (const f32x4*)(query + ((size_t)(lq * 8 + n) << 8) + c);
            lo[j] = __builtin_nontemporal_load(src);
            hi[j] = __builtin_nontemporal_load(src + 1);
        }
#pragma unroll
        for (int j = 0; j < 8; ++j) {
            uint4 r;
            r.x = pk2(lo[j].x, lo[j].y); r.y = pk2(lo[j].z, lo[j].w);
            r.z = pk2(hi[j].x, hi[j].y); r.w = pk2(hi[j].z, hi[j].w);
            qbf4[base + j] = r;
        }
    } else {
        const int wi = (b - 2174) * 256 + t;
        if (wi < WPN) {
            int j = wi >> 8, k = wi & 255;
            float v = (j < 256) ? W_off[k * 256 + j] : W_attn[k * 128 + (j - 256)];
            wtp[wi] = f2bf(v);
        } else {
            int wi2 = wi - WPN;
            int j = wi2 >> 8, k = wi2 & 255;
            wto[wi2] = f2bf(W_out[k * 256 + j]);
        }
    }
}

// ---------------------------------------------------------------------------
// MFMA GEMM: C(32768 x 384) = qbf(bf16) * Wt^T + bias.
// Block 128x128, 4 waves (2x2), wave tile 64x64 = 4x4 frags of 16x16x32.
// ---------------------------------------------------------------------------
__global__ __launch_bounds__(256) void proj_gemm(
    const u16* __restrict__ A, const u16* __restrict__ Bt,
    const float* __restrict__ b_off, const float* __restrict__ b_attn,
    float* __restrict__ C)
{
    const int t = threadIdx.x;
    const int wid = t >> 6, lane = t & 63;
    const int lr = lane & 15, lk = lane >> 4;
    const int mrow = blockIdx.x * 128 + (wid >> 1) * 64;
    const int ncol = blockIdx.y * 128 + (wid & 1) * 64;
    const int kO = lk * 8;

    f32x4 acc[4][4] = {};
#pragma unroll
    for (int kk = 0; kk < 8; ++kk) {
        bf16x8 a[4], b[4];
#pragma unroll
        for (int mi = 0; mi < 4; ++mi)
            a[mi] = *(const bf16x8*)(A + (size_t)(mrow + mi * 16 + lr) * 256 + kk * 32 + kO);
#pragma unroll
        for (int ni = 0; ni < 4; ++ni)
            b[ni] = *(const bf16x8*)(Bt + (size_t)(ncol + ni * 16 + lr) * 256 + kk * 32 + kO);
#pragma unroll
        for (int mi = 0; mi < 4; ++mi)
#pragma unroll
            for (int ni = 0; ni < 4; ++ni)
                acc[mi][ni] = __builtin_amdgcn_mfma_f32_16x16x32_bf16(a[mi], b[ni], acc[mi][ni], 0, 0, 0);
    }

#pragma unroll
    for (int ni = 0; ni < 4; ++ni) {
        int gcol = ncol + ni * 16 + lr;
        float bias = (gcol < 256) ? b_off[gcol] : b_attn[gcol - 256];
#pragma unroll
        for (int mi = 0; mi < 4; ++mi) {
            f32x4 v = acc[mi][ni];
#pragma unroll
            for (int r = 0; r < 4; ++r)
                C[(size_t)(mrow + mi * 16 + lk * 4 + r) * 384 + gcol] = v[r] + bias;
        }
    }
}

// ---------------------------------------------------------------------------
// Fused softmax + loc + bilinear gather (bf16 fm). 2 queries per block.
// Prologue: 256 threads -> (ql = t>>7, point = t&127): softmax (16-lane shfl),
// clamped corner BYTE offsets + premultiplied weights -> LDS.
// Main: 16 lanes/head = 4 point-groups x 4 lanes; lane reads uint4 (8 bf16 ch)
// per corner -> 16B requests, 16 loads/thread total.
// ---------------------------------------------------------------------------
__global__ __launch_bounds__(256) void sample_kernel(
    const u16* __restrict__ fmb,
    const float* __restrict__ proj,
    const float* __restrict__ refp,
    u16* __restrict__ mid)
{
    __shared__ i32x4 loff[256];
    __shared__ f32x4 lwv[256];
    const int t = threadIdx.x;
    const int ql = t >> 7, pt = t & 127;
    const int gq = blockIdx.x * 2 + ql;
    const int n = gq >> 12;

    {
        const int lp = pt & 15, l = lp >> 2;
        float lg = proj[(size_t)gq * 384 + 256 + pt];
        float m = lg;
#pragma unroll
        for (int msk = 1; msk < 16; msk <<= 1) m = fmaxf(m, __shfl_xor(m, msk));
        float e = __expf(lg - m);
        float s = e;
#pragma unroll
        for (int msk = 1; msk < 16; msk <<= 1) s += __shfl_xor(s, msk);
        float a = e / s;

        float ox = proj[(size_t)gq * 384 + 2 * pt];
        float oy = proj[(size_t)gq * 384 + 2 * pt + 1];
        int   Sl = (l == 0) ? 100 : (l == 1) ? 50 : (l == 2) ? 25 : 13;
        int   lb = (l == 0) ? 0 : (l == 1) ? 10000 : (l == 2) ? 12500 : 13125;
        float Sf = (float)Sl;
        float rx = refp[((size_t)gq * 4 + l) * 2 + 0];
        float ry = refp[((size_t)gq * 4 + l) * 2 + 1];
        float px = rx * Sf + ox - 0.5f;
        float py = ry * Sf + oy - 0.5f;
        float x0f = floorf(px), y0f = floorf(py);
        float wx = px - x0f, wy = py - y0f;
        int x0 = (int)x0f, y0 = (int)y0f;
        bool xv0 = (unsigned)x0 < (unsigned)Sl;
        bool xv1 = (unsigned)(x0 + 1) < (unsigned)Sl;
        bool yv0 = (unsigned)y0 < (unsigned)Sl;
        bool yv1 = (unsigned)(y0 + 1) < (unsigned)Sl;
        int x0c = min(max(x0, 0), Sl - 1), x1c = min(max(x0 + 1, 0), Sl - 1);
        int y0c = min(max(y0, 0), Sl - 1), y1c = min(max(y0 + 1, 0), Sl - 1);
        // BYTE offsets; per-pos stride = 8*256*2B = 4096
        int r0 = (lb + y0c * Sl) << 12, r1 = (lb + y1c * Sl) << 12;
        i32x4 o; f32x4 w;
        o.x = r0 + (x0c << 12); o.y = r0 + (x1c << 12);
        o.z = r1 + (x0c << 12); o.w = r1 + (x1c << 12);
        w.x = (xv0 && yv0) ? a * (1.f - wx) * (1.f - wy) : 0.f;
        w.y = (xv1 && yv0) ? a * wx * (1.f - wy) : 0.f;
        w.z = (xv0 && yv1) ? a * (1.f - wx) * wy : 0.f;
        w.w = (xv1 && yv1) ? a * wx * wy : 0.f;
        loff[t] = o;
        lwv[t] = w;
    }
    __syncthreads();

    const int h = pt >> 4, ll = pt & 15, g2 = ll >> 2, cl = ll & 3;
    const uint boff = (uint)(n * 512 + h * 64 + cl * 16);
    const char* __restrict__ fb = (const char*)fmb;

    float a0 = 0.f, a1 = 0.f, a2 = 0.f, a3 = 0.f;
    float a4 = 0.f, a5 = 0.f, a6 = 0.f, a7 = 0.f;
#pragma unroll
    for (int pi = 0; pi < 4; ++pi) {
        int idx = ql * 128 + h * 16 + g2 * 4 + pi;
        i32x4 o = loff[idx];
        f32x4 w = lwv[idx];
        uint4 v0 = *(const uint4*)(fb + (boff + (uint)o.x));
        uint4 v1 = *(const uint4*)(fb + (boff + (uint)o.y));
        uint4 v2 = *(const uint4*)(fb + (boff + (uint)o.z));
        uint4 v3 = *(const uint4*)(fb + (boff + (uint)o.w));
#define ACC8(u, wt)                                        \
        a0 += wt * __uint_as_float(u.x << 16);             \
        a1 += wt * __uint_as_float(u.x & 0xFFFF0000u);     \
        a2 += wt * __uint_as_float(u.y << 16);             \
        a3 += wt * __uint_as_float(u.y & 0xFFFF0000u);     \
        a4 += wt * __uint_as_float(u.z << 16);             \
        a5 += wt * __uint_as_float(u.z & 0xFFFF0000u);     \
        a6 += wt * __uint_as_float(u.w << 16);             \
        a7 += wt * __uint_as_float(u.w & 0xFFFF0000u);
        ACC8(v0, w.x) ACC8(v1, w.y) ACC8(v2, w.z) ACC8(v3, w.w)
#undef ACC8
    }
    // reduce across the 4 point-groups (lane bits 2 and 3)
#pragma unroll
    for (int msk = 4; msk <= 8; msk <<= 1) {
        a0 += __shfl_xor(a0, msk); a1 += __shfl_xor(a1, msk);
        a2 += __shfl_xor(a2, msk); a3 += __shfl_xor(a3, msk);
        a4 += __shfl_xor(a4, msk); a5 += __shfl_xor(a5, msk);
        a6 += __shfl_xor(a6, msk); a7 += __shfl_xor(a7, msk);
    }

    if (ll < 4) {
        uint4 r;
        r.x = pk2(a0, a1); r.y = pk2(a2, a3);
        r.z = pk2(a4, a5); r.w = pk2(a6, a7);
        ((uint4*)mid)[(size_t)gq * 32 + h * 4 + cl] = r;
    }
}

// ---------------------------------------------------------------------------
// MFMA GEMM: out = mid(32768 x 256, bf16) * W_out^T + b_out, transposed write.
// ---------------------------------------------------------------------------
__global__ __launch_bounds__(256) void out_gemm(
    const u16* __restrict__ A, const u16* __restrict__ Bt,
    const float* __restrict__ b_out,
    float* __restrict__ out)
{
    const int t = threadIdx.x;
    const int wid = t >> 6, lane = t & 63;
    const int lr = lane & 15, lk = lane >> 4;
    const int mrow = blockIdx.x * 128 + (wid >> 1) * 64;
    const int ncol = blockIdx.y * 128 + (wid & 1) * 64;
    const int kO = lk * 8;

    f32x4 acc[4][4] = {};
#pragma unroll
    for (int kk = 0; kk < 8; ++kk) {
        bf16x8 a[4], b[4];
#pragma unroll
        for (int mi = 0; mi < 4; ++mi)
            a[mi] = *(const bf16x8*)(A + (size_t)(mrow + mi * 16 + lr) * 256 + kk * 32 + kO);
#pragma unroll
        for (int ni = 0; ni < 4; ++ni)
            b[ni] = *(const bf16x8*)(Bt + (size_t)(ncol + ni * 16 + lr) * 256 + kk * 32 + kO);
#pragma unroll
        for (int mi = 0; mi < 4; ++mi)
#pragma unroll
            for (int ni = 0; ni < 4; ++ni)
                acc[mi][ni] = __builtin_amdgcn_mfma_f32_16x16x32_bf16(a[mi], b[ni], acc[mi][ni], 0, 0, 0);
    }

#pragma unroll
    for (int ni = 0; ni < 4; ++ni) {
        int gcol = ncol + ni * 16 + lr;
        float bias = b_out[gcol];
#pragma unroll
        for (int mi = 0; mi < 4; ++mi) {
            f32x4 v = acc[mi][ni];
#pragma unroll
            for (int r = 0; r < 4; ++r) {
                int grow = mrow + mi * 16 + lk * 4 + r;
                int nn = grow >> 12, lq = grow & 4095;
                out[(size_t)(lq * 8 + nn) * 256 + gcol] = v[r] + bias;
            }
        }
    }
}

extern "C" void kernel_launch(void* const* d_in, const int* in_sizes, int n_in,
                              void* d_out, int out_size, void* d_ws, size_t ws_size,
                              hipStream_t stream) {
    const float* query  = (const float*)d_in[0];
    const float* refp   = (const float*)d_in[1];
    const float* fm     = (const float*)d_in[2];
    const float* W_off  = (const float*)d_in[4];
    const float* b_off  = (const float*)d_in[5];
    const float* W_attn = (const float*)d_in[6];
    const float* b_attn = (const float*)d_in[7];
    const float* W_out  = (const float*)d_in[8];
    const float* b_out  = (const float*)d_in[9];
    float* out = (float*)d_out;

    // workspace (~122 MB). qbf ALIASES mid: qbf is written by prep, consumed
    // by proj_gemm; mid is first written by sample (after proj) - disjoint
    // live ranges.
    float* ws_proj = (float*)d_ws;                        // 32768*384 f32 (50.3 MB)
    u16*   wtp     = (u16*)(ws_proj + (size_t)NLQ * 384); // 384*256 bf16
    u16*   wto     = wtp + (size_t)WPN;                   // 256*256 bf16
    u16*   mid     = wto + (size_t)WON;                   // 32768*256 bf16 (16.8 MB)
    u16*   qbf     = mid;                                 // alias (see above)
    u16*   fmb     = mid + (size_t)NLQ * 256;             // 13294*2048 bf16 (54.5 MB)

    prep_kernel<<<2814, 256, 0, stream>>>((const f32x4*)fm, (uint4*)fmb,
                                          query, (uint4*)qbf,
                                          W_off, W_attn, W_out, wtp, wto);
    proj_gemm<<<dim3(256, 3), 256, 0, stream>>>(qbf, wtp, b_off, b_attn, ws_proj);
    sample_kernel<<<NLQ / 2, 256, 0, stream>>>(fmb, ws_proj, refp, mid);
    out_gemm<<<dim3(256, 2), 256, 0, stream>>>(mid, wto, b_out, out);
}

// Round 11
// 155.106 us; speedup vs baseline: 1.3925x; 1.3925x over previous
//
#include <hip/hip_runtime.h>
#include <hip/hip_fp16.h>

typedef unsigned short u16;
typedef __attribute__((ext_vector_type(8))) _Float16 f16x8;
typedef __attribute__((ext_vector_type(4))) float f32x4;
typedef __attribute__((ext_vector_type(4))) int   i32x4;

#define NLQ 32768          // N*Lq
#define WPN (384*256)      // proj weight elements
#define WON (256*256)      // out weight elements
#define FMU 3403264        // fm 32B-units = 13294*8*256/8

static __device__ __forceinline__ uint pkh(float a, float b) {
    __half2 h = __floats2half2_rn(a, b);
    return *reinterpret_cast<uint*>(&h);
}
static __device__ __forceinline__ u16 f2h(float a) {
    __half h = __float2half_rn(a);
    return *reinterpret_cast<u16*>(&h);
}
static __device__ __forceinline__ __half2 bits2h2(uint u) {
    return *reinterpret_cast<__half2*>(&u);
}
static __device__ __forceinline__ __half2 shfl_xor_h2(__half2 v, int m) {
    int i = *reinterpret_cast<int*>(&v);
    i = __shfl_xor(i, m);
    return *reinterpret_cast<__half2*>(&i);
}

// ---------------------------------------------------------------------------
// Prep (one kernel, 3 sections, all wave-coalesced u = base + t + j*256):
//  A [0,1663):     fm f32 -> f16 (same (pos,n,c) layout).
//  B [1663,2175):  query -> qh[(n*4096+lq)*256+c] f16 (transposed rows).
//  C [2175,2815):  W transposes -> wtp[j][k], wto[j][k] f16.
// ---------------------------------------------------------------------------
__global__ __launch_bounds__(256) void prep_kernel(
    const f32x4* __restrict__ fm, uint4* __restrict__ fmb,
    const float* __restrict__ query, uint4* __restrict__ qh4,
    const float* __restrict__ W_off, const float* __restrict__ W_attn,
    const float* __restrict__ W_out,
    u16* __restrict__ wtp, u16* __restrict__ wto)
{
    const int b = blockIdx.x, t = threadIdx.x;
    if (b < 1663) {
        const int base = b * 2048 + t;
#pragma unroll
        for (int j = 0; j < 8; ++j) {
            int u = base + j * 256;
            if (u < FMU) {
                f32x4 lo = __builtin_nontemporal_load(fm + 2 * u);
                f32x4 hi = __builtin_nontemporal_load(fm + 2 * u + 1);
                uint4 r;
                r.x = pkh(lo.x, lo.y); r.y = pkh(lo.z, lo.w);
                r.z = pkh(hi.x, hi.y); r.w = pkh(hi.z, hi.w);
                fmb[u] = r;
            }
        }
    } else if (b < 2175) {
        const int base = (b - 1663) * 2048 + t;   // 512*2048 = 1,048,576 exact
#pragma unroll
        for (int j = 0; j < 8; ++j) {
            int u = base + j * 256;
            int gq = u >> 5, c = (u & 31) * 8;
            int lq = gq & 4095, n = gq >> 12;
            const f32x4* src = (const f32x4*)(query + ((size_t)(lq * 8 + n) << 8) + c);
            f32x4 lo = __builtin_nontemporal_load(src);
            f32x4 hi = __builtin_nontemporal_load(src + 1);
            uint4 r;
            r.x = pkh(lo.x, lo.y); r.y = pkh(lo.z, lo.w);
            r.z = pkh(hi.x, hi.y); r.w = pkh(hi.z, hi.w);
            qh4[u] = r;
        }
    } else {
        const int wi = (b - 2175) * 256 + t;
        if (wi < WPN) {
            int j = wi >> 8, k = wi & 255;
            float v = (j < 256) ? W_off[k * 256 + j] : W_attn[k * 128 + (j - 256)];
            wtp[wi] = f2h(v);
        } else {
            int wi2 = wi - WPN;
            int j = wi2 >> 8, k = wi2 & 255;
            wto[wi2] = f2h(W_out[k * 256 + j]);
        }
    }
}

// ---------------------------------------------------------------------------
// MFMA GEMM: C(32768 x 384, f16) = qh(f16) * Wt^T + bias.
// Block 128x128, 4 waves (2x2), wave tile 64x64 = 4x4 frags of 16x16x32.
// ---------------------------------------------------------------------------
__global__ __launch_bounds__(256) void proj_gemm(
    const u16* __restrict__ A, const u16* __restrict__ Bt,
    const float* __restrict__ b_off, const float* __restrict__ b_attn,
    u16* __restrict__ C)
{
    const int t = threadIdx.x;
    const int wid = t >> 6, lane = t & 63;
    const int lr = lane & 15, lk = lane >> 4;
    const int mrow = blockIdx.x * 128 + (wid >> 1) * 64;
    const int ncol = blockIdx.y * 128 + (wid & 1) * 64;
    const int kO = lk * 8;

    f32x4 acc[4][4] = {};
#pragma unroll
    for (int kk = 0; kk < 8; ++kk) {
        f16x8 a[4], b[4];
#pragma unroll
        for (int mi = 0; mi < 4; ++mi)
            a[mi] = *(const f16x8*)(A + (size_t)(mrow + mi * 16 + lr) * 256 + kk * 32 + kO);
#pragma unroll
        for (int ni = 0; ni < 4; ++ni)
            b[ni] = *(const f16x8*)(Bt + (size_t)(ncol + ni * 16 + lr) * 256 + kk * 32 + kO);
#pragma unroll
        for (int mi = 0; mi < 4; ++mi)
#pragma unroll
            for (int ni = 0; ni < 4; ++ni)
                acc[mi][ni] = __builtin_amdgcn_mfma_f32_16x16x32_f16(a[mi], b[ni], acc[mi][ni], 0, 0, 0);
    }

#pragma unroll
    for (int ni = 0; ni < 4; ++ni) {
        int gcol = ncol + ni * 16 + lr;
        float bias = (gcol < 256) ? b_off[gcol] : b_attn[gcol - 256];
#pragma unroll
        for (int mi = 0; mi < 4; ++mi) {
            f32x4 v = acc[mi][ni];
#pragma unroll
            for (int r = 0; r < 4; ++r)
                C[(size_t)(mrow + mi * 16 + lk * 4 + r) * 384 + gcol] = f2h(v[r] + bias);
        }
    }
}

// ---------------------------------------------------------------------------
// Fused softmax + loc + bilinear gather (f16 fm, packed-f16 accumulate).
// 2 queries per block. Prologue: (ql = t>>7, point = t&127): softmax (16-lane
// shfl), clamped corner BYTE offsets + attention*bilinear weights broadcast
// as half2 -> LDS. Main: 16 lanes/head; lane reads uint4 (8 f16 ch) per
// corner; 4 __hfma2 per corner (64 packed FMA total).
// ---------------------------------------------------------------------------
__global__ __launch_bounds__(256) void sample_kernel(
    const u16* __restrict__ fmb,
    const u16* __restrict__ proj,
    const float* __restrict__ refp,
    u16* __restrict__ mid)
{
    __shared__ i32x4 loff[256];
    __shared__ i32x4 lwp[256];
    const int t = threadIdx.x;
    const int ql = t >> 7, pt = t & 127;
    const int gq = blockIdx.x * 2 + ql;
    const int n = gq >> 12;

    {
        const int lp = pt & 15, l = lp >> 2;
        float lg = __half2float(__ushort_as_half(proj[(size_t)gq * 384 + 256 + pt]));
        float m = lg;
#pragma unroll
        for (int msk = 1; msk < 16; msk <<= 1) m = fmaxf(m, __shfl_xor(m, msk));
        float e = __expf(lg - m);
        float s = e;
#pragma unroll
        for (int msk = 1; msk < 16; msk <<= 1) s += __shfl_xor(s, msk);
        float a = e / s;

        float ox = __half2float(__ushort_as_half(proj[(size_t)gq * 384 + 2 * pt]));
        float oy = __half2float(__ushort_as_half(proj[(size_t)gq * 384 + 2 * pt + 1]));
        int   Sl = (l == 0) ? 100 : (l == 1) ? 50 : (l == 2) ? 25 : 13;
        int   lb = (l == 0) ? 0 : (l == 1) ? 10000 : (l == 2) ? 12500 : 13125;
        float Sf = (float)Sl;
        float rx = refp[((size_t)gq * 4 + l) * 2 + 0];
        float ry = refp[((size_t)gq * 4 + l) * 2 + 1];
        float px = rx * Sf + ox - 0.5f;
        float py = ry * Sf + oy - 0.5f;
        float x0f = floorf(px), y0f = floorf(py);
        float wx = px - x0f, wy = py - y0f;
        int x0 = (int)x0f, y0 = (int)y0f;
        bool xv0 = (unsigned)x0 < (unsigned)Sl;
        bool xv1 = (unsigned)(x0 + 1) < (unsigned)Sl;
        bool yv0 = (unsigned)y0 < (unsigned)Sl;
        bool yv1 = (unsigned)(y0 + 1) < (unsigned)Sl;
        int x0c = min(max(x0, 0), Sl - 1), x1c = min(max(x0 + 1, 0), Sl - 1);
        int y0c = min(max(y0, 0), Sl - 1), y1c = min(max(y0 + 1, 0), Sl - 1);
        // BYTE offsets; per-pos stride = 8*256*2B = 4096
        int r0 = (lb + y0c * Sl) << 12, r1 = (lb + y1c * Sl) << 12;
        i32x4 o;
        o.x = r0 + (x0c << 12); o.y = r0 + (x1c << 12);
        o.z = r1 + (x0c << 12); o.w = r1 + (x1c << 12);
        float w0 = (xv0 && yv0) ? a * (1.f - wx) * (1.f - wy) : 0.f;
        float w1 = (xv1 && yv0) ? a * wx * (1.f - wy) : 0.f;
        float w2 = (xv0 && yv1) ? a * (1.f - wx) * wy : 0.f;
        float w3 = (xv1 && yv1) ? a * wx * wy : 0.f;
        i32x4 wp;
        wp.x = (int)pkh(w0, w0); wp.y = (int)pkh(w1, w1);
        wp.z = (int)pkh(w2, w2); wp.w = (int)pkh(w3, w3);
        loff[t] = o;
        lwp[t] = wp;
    }
    __syncthreads();

    const int h = pt >> 4, ll = pt & 15, g2 = ll >> 2, cl = ll & 3;
    const uint boff = (uint)(n * 512 + h * 64 + cl * 16);
    const char* __restrict__ fb = (const char*)fmb;

    __half2 z = __float2half2_rn(0.f);
    __half2 a01 = z, a23 = z, a45 = z, a67 = z;
#pragma unroll
    for (int pi = 0; pi < 4; ++pi) {
        int idx = ql * 128 + h * 16 + g2 * 4 + pi;
        i32x4 o = loff[idx];
        i32x4 wp = lwp[idx];
        uint4 v0 = *(const uint4*)(fb + (boff + (uint)o.x));
        uint4 v1 = *(const uint4*)(fb + (boff + (uint)o.y));
        uint4 v2 = *(const uint4*)(fb + (boff + (uint)o.z));
        uint4 v3 = *(const uint4*)(fb + (boff + (uint)o.w));
        const uint4* vv[4] = {&v0, &v1, &v2, &v3};
        const int    ww[4] = {wp.x, wp.y, wp.z, wp.w};
#pragma unroll
        for (int cn = 0; cn < 4; ++cn) {
            __half2 wh = bits2h2((uint)ww[cn]);
            uint4 vb = *vv[cn];
            a01 = __hfma2(bits2h2(vb.x), wh, a01);
            a23 = __hfma2(bits2h2(vb.y), wh, a23);
            a45 = __hfma2(bits2h2(vb.z), wh, a45);
            a67 = __hfma2(bits2h2(vb.w), wh, a67);
        }
    }
    // reduce across the 4 point-groups (lane bits 2 and 3)
#pragma unroll
    for (int msk = 4; msk <= 8; msk <<= 1) {
        a01 = __hadd2(a01, shfl_xor_h2(a01, msk));
        a23 = __hadd2(a23, shfl_xor_h2(a23, msk));
        a45 = __hadd2(a45, shfl_xor_h2(a45, msk));
        a67 = __hadd2(a67, shfl_xor_h2(a67, msk));
    }

    if (ll < 4) {
        uint4 r;
        r.x = *reinterpret_cast<uint*>(&a01);
        r.y = *reinterpret_cast<uint*>(&a23);
        r.z = *reinterpret_cast<uint*>(&a45);
        r.w = *reinterpret_cast<uint*>(&a67);
        ((uint4*)mid)[(size_t)gq * 32 + h * 4 + cl] = r;
    }
}

// ---------------------------------------------------------------------------
// MFMA GEMM: out = mid(32768 x 256, f16) * W_out^T + b_out, transposed write.
// ---------------------------------------------------------------------------
__global__ __launch_bounds__(256) void out_gemm(
    const u16* __restrict__ A, const u16* __restrict__ Bt,
    const float* __restrict__ b_out,
    float* __restrict__ out)
{
    const int t = threadIdx.x;
    const int wid = t >> 6, lane = t & 63;
    const int lr = lane & 15, lk = lane >> 4;
    const int mrow = blockIdx.x * 128 + (wid >> 1) * 64;
    const int ncol = blockIdx.y * 128 + (wid & 1) * 64;
    const int kO = lk * 8;

    f32x4 acc[4][4] = {};
#pragma unroll
    for (int kk = 0; kk < 8; ++kk) {
        f16x8 a[4], b[4];
#pragma unroll
        for (int mi = 0; mi < 4; ++mi)
            a[mi] = *(const f16x8*)(A + (size_t)(mrow + mi * 16 + lr) * 256 + kk * 32 + kO);
#pragma unroll
        for (int ni = 0; ni < 4; ++ni)
            b[ni] = *(const f16x8*)(Bt + (size_t)(ncol + ni * 16 + lr) * 256 + kk * 32 + kO);
#pragma unroll
        for (int mi = 0; mi < 4; ++mi)
#pragma unroll
            for (int ni = 0; ni < 4; ++ni)
                acc[mi][ni] = __builtin_amdgcn_mfma_f32_16x16x32_f16(a[mi], b[ni], acc[mi][ni], 0, 0, 0);
    }

#pragma unroll
    for (int ni = 0; ni < 4; ++ni) {
        int gcol = ncol + ni * 16 + lr;
        float bias = b_out[gcol];
#pragma unroll
        for (int mi = 0; mi < 4; ++mi) {
            f32x4 v = acc[mi][ni];
#pragma unroll
            for (int r = 0; r < 4; ++r) {
                int grow = mrow + mi * 16 + lk * 4 + r;
                int nn = grow >> 12, lq = grow & 4095;
                out[(size_t)(lq * 8 + nn) * 256 + gcol] = v[r] + bias;
            }
        }
    }
}

extern "C" void kernel_launch(void* const* d_in, const int* in_sizes, int n_in,
                              void* d_out, int out_size, void* d_ws, size_t ws_size,
                              hipStream_t stream) {
    const float* query  = (const float*)d_in[0];
    const float* refp   = (const float*)d_in[1];
    const float* fm     = (const float*)d_in[2];
    const float* W_off  = (const float*)d_in[4];
    const float* b_off  = (const float*)d_in[5];
    const float* W_attn = (const float*)d_in[6];
    const float* b_attn = (const float*)d_in[7];
    const float* W_out  = (const float*)d_in[8];
    const float* b_out  = (const float*)d_in[9];
    float* out = (float*)d_out;

    // workspace (~97 MB), all f16. qh ALIASES mid (disjoint live ranges:
    // qh written by prep, read by proj; mid first written by sample).
    u16* ws_proj = (u16*)d_ws;                 // 32768*384 f16 (25.2 MB)
    u16* wtp     = ws_proj + (size_t)NLQ * 384;
    u16* wto     = wtp + (size_t)WPN;
    u16* mid     = wto + (size_t)WON;          // 32768*256 f16 (16.8 MB)
    u16* qh      = mid;                        // alias (see above)
    u16* fmb     = mid + (size_t)NLQ * 256;    // 13294*2048 f16 (54.5 MB)

    prep_kernel<<<2815, 256, 0, stream>>>((const f32x4*)fm, (uint4*)fmb,
                                          query, (uint4*)qh,
                                          W_off, W_attn, W_out, wtp, wto);
    proj_gemm<<<dim3(256, 3), 256, 0, stream>>>(qh, wtp, b_off, b_attn, ws_proj);
    sample_kernel<<<NLQ / 2, 256, 0, stream>>>(fmb, ws_proj, refp, mid);
    out_gemm<<<dim3(256, 2), 256, 0, stream>>>(mid, wto, b_out, out);
}